// Round 1
// baseline (285.352 us; speedup 1.0000x reference)
//
#include <hip/hip_runtime.h>
#include <hip/hip_bf16.h>
#include <stdint.h>

// Problem dims (fixed by setup_inputs)
#define B_N 4096
#define S_N 8192
#define KX  256
#define KY  128
// Tiling
#define BM  32
#define BN  64
#define SSPLIT 4
#define SRANGE (S_N / SSPLIT)      // 2048
#define STILES (SRANGE / BN)       // 32

typedef __bf16 bf16x8 __attribute__((ext_vector_type(8)));
typedef float  f32x4  __attribute__((ext_vector_type(4)));

// ---- workspace byte offsets ----
#define OFF_XH   ((size_t)0)            // 4096*256*2 = 2 MB
#define OFF_XL   ((size_t)2097152)
#define OFF_YH   ((size_t)4194304)      // 4096*128*2 = 1 MB
#define OFF_YL   ((size_t)5242880)
#define OFF_SXH  ((size_t)6291456)      // 8192*256*2 = 4 MB
#define OFF_SXL  ((size_t)10485760)
#define OFF_SYH  ((size_t)14680064)     // 8192*128*2 = 2 MB
#define OFF_SYL  ((size_t)16777216)
#define OFF_NX   ((size_t)18874368)     // 4096 f32
#define OFF_NY   (OFF_NX + 16384)
#define OFF_NSX  (OFF_NY + 16384)       // 8192 f32
#define OFF_NSY  (OFF_NSX + 32768)
#define OFF_PART (OFF_NSY + 32768)      // [3][4096][8][2] f32 = 768 KB
// total ws use ~19.8 MB

__device__ __forceinline__ void gl2lds16(const void* g, void* l) {
  // async global->LDS, 16B per lane; LDS dest = wave-uniform base + lane*16
  typedef const __attribute__((address_space(1))) unsigned int* gp_t;
  typedef __attribute__((address_space(3))) unsigned int* lp_t;
  __builtin_amdgcn_global_load_lds((gp_t)g, (lp_t)l, 16, 0, 0);
}

// fp32 -> (bf16 hi, bf16 lo) split + exact fp32 row norms. One wave per row.
__global__ void conv_norm(const float* __restrict__ src,
                          __hip_bfloat16* __restrict__ hi,
                          __hip_bfloat16* __restrict__ lo,
                          float* __restrict__ nrm, int K) {
  int row  = blockIdx.x;
  int lane = threadIdx.x;
  const float* r = src + (size_t)row * K;
  float acc = 0.f;
  for (int k = lane; k < K; k += 64) {
    float v = r[k];
    acc = fmaf(v, v, acc);
    __hip_bfloat16 h = __float2bfloat16(v);
    float hf = __bfloat162float(h);
    __hip_bfloat16 l = __float2bfloat16(v - hf);
    hi[(size_t)row * K + k] = h;
    lo[(size_t)row * K + k] = l;
  }
  #pragma unroll
  for (int o = 32; o > 0; o >>= 1) acc += __shfl_down(acc, o);
  if (lane == 0) nrm[row] = acc;
}

__global__ __launch_bounds__(256, 2) void mie_main(const char* __restrict__ ws,
                                                   float* __restrict__ part) {
  __shared__ __align__(16) char smem[65536];
  enum { AXH = 0, AXL = 16384, AYH = 32768, AYL = 40960, BH = 49152, BL = 57344 };

  const int tid  = threadIdx.x;
  const int lane = tid & 63;
  const int wave = tid >> 6;
  const int c    = lane & 15;
  const int q    = lane >> 4;
  const int wm   = wave >> 1;
  const int wn   = wave & 1;
  const int bm0  = blockIdx.x * BM;
  const int sp   = blockIdx.y;
  const int sbase = sp * SRANGE;

  const char* xh  = ws + OFF_XH;
  const char* xl  = ws + OFF_XL;
  const char* yh  = ws + OFF_YH;
  const char* yl  = ws + OFF_YL;
  const char* sxh = ws + OFF_SXH;
  const char* sxl = ws + OFF_SXL;
  const char* syh = ws + OFF_SYH;
  const char* syl = ws + OFF_SYL;
  const float* nx  = (const float*)(ws + OFF_NX);
  const float* ny  = (const float*)(ws + OFF_NY);
  const float* nsx = (const float*)(ws + OFF_NSX);
  const float* nsy = (const float*)(ws + OFF_NSY);

  // ---- stage resident A row-tiles (x,y hi/lo), 16B-granule XOR swizzle ----
  // layout: row r (W bytes) holds logical granule gk at physical slot gk^(r&7)
  #pragma unroll
  for (int i = 0; i < 4; ++i) {           // Axh/Axl: 16 KB each
    int g  = (wave * 4 + i) * 64 + lane;
    int r  = g >> 5;
    int p  = g & 31;
    int gk = p ^ (r & 7);
    size_t go = (size_t)(bm0 + r) * 512 + (size_t)gk * 16;
    gl2lds16(xh + go, smem + AXH + (wave * 4 + i) * 1024);
    gl2lds16(xl + go, smem + AXL + (wave * 4 + i) * 1024);
  }
  #pragma unroll
  for (int i = 0; i < 2; ++i) {           // Ayh/Ayl: 8 KB each
    int g  = (wave * 2 + i) * 64 + lane;
    int r  = g >> 4;
    int p  = g & 15;
    int gk = p ^ (r & 7);
    size_t go = (size_t)(bm0 + r) * 256 + (size_t)gk * 16;
    gl2lds16(yh + go, smem + AYH + (wave * 2 + i) * 1024);
    gl2lds16(yl + go, smem + AYL + (wave * 2 + i) * 1024);
  }

  // B chunk stage: 64 s-rows x 32 k (64B/row), swizzle slot j' = j ^ ((r>>1)&3)
  auto stage_chunk = [&](int st, int ph, int buf) {
    const char* sh; const char* sl; int rb, k0b;
    if (ph < 8) { sh = sxh; sl = sxl; rb = 512; k0b = ph * 64; }
    else        { sh = syh; sl = syl; rb = 256; k0b = (ph - 8) * 64; }
    int s0 = sbase + st * BN;
    int r  = wave * 16 + (lane >> 2);
    int j  = (lane & 3) ^ ((r >> 1) & 3);
    size_t go = (size_t)(s0 + r) * rb + (size_t)(k0b + j * 16);
    gl2lds16(sh + go, smem + BH + buf * 4096 + wave * 1024);
    gl2lds16(sl + go, smem + BL + buf * 4096 + wave * 1024);
  };

  // lane-invariant fragment offsets
  const int m    = wm * 16 + c;
  const int m7   = m & 7;
  const int n0   = wn * 32 + c;
  const int n1   = n0 + 16;
  const int boff0 = n0 * 64 + ((q ^ ((n0 >> 1) & 3)) * 16);
  const int boff1 = n1 * 64 + ((q ^ ((n1 >> 1) & 3)) * 16);

  float nx4[4], ny4[4];
  #pragma unroll
  for (int r = 0; r < 4; ++r) {
    nx4[r] = nx[bm0 + wm * 16 + q * 4 + r];
    ny4[r] = ny[bm0 + wm * 16 + q * 4 + r];
  }

  // online-lse state per lane: 4 rows x {xy, x, y}
  float stm[4][3], sts[4][3];
  #pragma unroll
  for (int r = 0; r < 4; ++r)
    #pragma unroll
    for (int j = 0; j < 3; ++j) { stm[r][j] = -__builtin_inff(); sts[r][j] = 0.f; }

  auto upd1 = [](float& m_, float& s_, float v) {
    if (v <= m_) {
      s_ += __expf(v - m_);
    } else {
      s_ = s_ * __expf(m_ - v) + 1.0f;   // first hit: 0*exp(-inf)=0, then +1
      m_ = v;
    }
  };

  int nst = 0, nph = 1;       // next chunk to prefetch (chunk 1)
  stage_chunk(0, 0, 0);       // chunk 0 -> buf 0
  int parity = 0;
  __syncthreads();            // drains A staging + chunk 0

  for (int st = 0; st < STILES; ++st) {
    f32x4 ax0 = {0.f,0.f,0.f,0.f}, ax1 = {0.f,0.f,0.f,0.f};
    f32x4 ay0 = {0.f,0.f,0.f,0.f}, ay1 = {0.f,0.f,0.f,0.f};
    #pragma unroll
    for (int ph = 0; ph < 12; ++ph) {     // 8 x-chunks (K=256) + 4 y-chunks (K=128)
      if (nst < STILES) {                 // prefetch next chunk into other buffer
        stage_chunk(nst, nph, parity ^ 1);
        if (++nph == 12) { nph = 0; ++nst; }
      }
      const char* bhp = smem + BH + parity * 4096;
      const char* blp = smem + BL + parity * 4096;
      bf16x8 b0h = *(const bf16x8*)(bhp + boff0);
      bf16x8 b1h = *(const bf16x8*)(bhp + boff1);
      bf16x8 b0l = *(const bf16x8*)(blp + boff0);
      bf16x8 b1l = *(const bf16x8*)(blp + boff1);
      if (ph < 8) {
        int slot = ((ph * 4 + q) ^ m7) * 16;
        bf16x8 ah = *(const bf16x8*)(smem + AXH + m * 512 + slot);
        bf16x8 al = *(const bf16x8*)(smem + AXL + m * 512 + slot);
        ax0 = __builtin_amdgcn_mfma_f32_16x16x32_bf16(ah, b0h, ax0, 0, 0, 0);
        ax0 = __builtin_amdgcn_mfma_f32_16x16x32_bf16(ah, b0l, ax0, 0, 0, 0);
        ax0 = __builtin_amdgcn_mfma_f32_16x16x32_bf16(al, b0h, ax0, 0, 0, 0);
        ax1 = __builtin_amdgcn_mfma_f32_16x16x32_bf16(ah, b1h, ax1, 0, 0, 0);
        ax1 = __builtin_amdgcn_mfma_f32_16x16x32_bf16(ah, b1l, ax1, 0, 0, 0);
        ax1 = __builtin_amdgcn_mfma_f32_16x16x32_bf16(al, b1h, ax1, 0, 0, 0);
      } else {
        int kc = ph - 8;
        int slot = ((kc * 4 + q) ^ m7) * 16;
        bf16x8 ah = *(const bf16x8*)(smem + AYH + m * 256 + slot);
        bf16x8 al = *(const bf16x8*)(smem + AYL + m * 256 + slot);
        ay0 = __builtin_amdgcn_mfma_f32_16x16x32_bf16(ah, b0h, ay0, 0, 0, 0);
        ay0 = __builtin_amdgcn_mfma_f32_16x16x32_bf16(ah, b0l, ay0, 0, 0, 0);
        ay0 = __builtin_amdgcn_mfma_f32_16x16x32_bf16(al, b0h, ay0, 0, 0, 0);
        ay1 = __builtin_amdgcn_mfma_f32_16x16x32_bf16(ah, b1h, ay1, 0, 0, 0);
        ay1 = __builtin_amdgcn_mfma_f32_16x16x32_bf16(ah, b1l, ay1, 0, 0, 0);
        ay1 = __builtin_amdgcn_mfma_f32_16x16x32_bf16(al, b1h, ay1, 0, 0, 0);
      }
      parity ^= 1;
      __syncthreads();
    }
    // ---- epilogue: sdx/sdy + online logsumexp update ----
    int s0 = sbase + st * BN;
    float nsx0 = nsx[s0 + n0], nsx1 = nsx[s0 + n1];
    float nsy0 = nsy[s0 + n0], nsy1 = nsy[s0 + n1];
    #pragma unroll
    for (int r = 0; r < 4; ++r) {
      float sdx0 = nx4[r] + nsx0 - 2.0f * ax0[r];
      float sdy0 = ny4[r] + nsy0 - 2.0f * ay0[r];
      float tx = -0.5f * sdx0, ty = -0.5f * sdy0;
      upd1(stm[r][0], sts[r][0], tx + ty);
      upd1(stm[r][1], sts[r][1], tx);
      upd1(stm[r][2], sts[r][2], ty);
      float sdx1 = nx4[r] + nsx1 - 2.0f * ax1[r];
      float sdy1 = ny4[r] + nsy1 - 2.0f * ay1[r];
      tx = -0.5f * sdx1; ty = -0.5f * sdy1;
      upd1(stm[r][0], sts[r][0], tx + ty);
      upd1(stm[r][1], sts[r][1], tx);
      upd1(stm[r][2], sts[r][2], ty);
    }
  }

  // ---- merge across the 16 column-lanes of each quad; write partials ----
  #pragma unroll
  for (int r = 0; r < 4; ++r) {
    #pragma unroll
    for (int j = 0; j < 3; ++j) {
      float mm = stm[r][j], ss = sts[r][j];
      #pragma unroll
      for (int msk = 1; msk < 16; msk <<= 1) {
        float om = __shfl_xor(mm, msk);
        float os = __shfl_xor(ss, msk);
        float nm = fmaxf(mm, om);
        ss = ss * __expf(mm - nm) + os * __expf(om - nm);
        mm = nm;
      }
      if (c == 0) {
        int row = bm0 + wm * 16 + q * 4 + r;
        size_t idx = (((size_t)j * B_N + row) * 8 + (size_t)(sp * 2 + wn)) * 2;
        part[idx]     = mm;
        part[idx + 1] = ss;
      }
    }
  }
}

__global__ void mie_finalize(const float* __restrict__ part, float* __restrict__ out) {
  __shared__ float red[256];
  int tid = threadIdx.x;
  float local = 0.f;
  for (int row = tid; row < B_N; row += 256) {
    float v[3];
    #pragma unroll
    for (int j = 0; j < 3; ++j) {
      float m = -__builtin_inff(), s = 0.f;
      #pragma unroll
      for (int p = 0; p < 8; ++p) {
        size_t idx = (((size_t)j * B_N + row) * 8 + p) * 2;
        float pm = part[idx], ps = part[idx + 1];
        float nm = fmaxf(m, pm);
        s = s * __expf(m - nm) + ps * __expf(pm - nm);
        m = nm;
      }
      v[j] = m + __logf(s);
    }
    local += v[0] - v[1] - v[2];   // logA constants cancel exactly
  }
  red[tid] = local;
  __syncthreads();
  for (int o = 128; o > 0; o >>= 1) {
    if (tid < o) red[tid] += red[tid + o];
    __syncthreads();
  }
  if (tid == 0) out[0] = red[0] * (1.0f / B_N);
}

extern "C" void kernel_launch(void* const* d_in, const int* in_sizes, int n_in,
                              void* d_out, int out_size, void* d_ws, size_t ws_size,
                              hipStream_t stream) {
  (void)in_sizes; (void)n_in; (void)out_size; (void)ws_size;
  const float* x  = (const float*)d_in[0];
  const float* y  = (const float*)d_in[1];
  const float* xs = (const float*)d_in[2];
  const float* ys = (const float*)d_in[3];
  char* ws = (char*)d_ws;

  conv_norm<<<B_N, 64, 0, stream>>>(x,  (__hip_bfloat16*)(ws + OFF_XH),
                                    (__hip_bfloat16*)(ws + OFF_XL),
                                    (float*)(ws + OFF_NX), KX);
  conv_norm<<<B_N, 64, 0, stream>>>(y,  (__hip_bfloat16*)(ws + OFF_YH),
                                    (__hip_bfloat16*)(ws + OFF_YL),
                                    (float*)(ws + OFF_NY), KY);
  conv_norm<<<S_N, 64, 0, stream>>>(xs, (__hip_bfloat16*)(ws + OFF_SXH),
                                    (__hip_bfloat16*)(ws + OFF_SXL),
                                    (float*)(ws + OFF_NSX), KX);
  conv_norm<<<S_N, 64, 0, stream>>>(ys, (__hip_bfloat16*)(ws + OFF_SYH),
                                    (__hip_bfloat16*)(ws + OFF_SYL),
                                    (float*)(ws + OFF_NSY), KY);

  mie_main<<<dim3(B_N / BM, SSPLIT), 256, 0, stream>>>(ws, (float*)(ws + OFF_PART));
  mie_finalize<<<1, 256, 0, stream>>>((const float*)(ws + OFF_PART), (float*)d_out);
}

// Round 3
// 252.282 us; speedup vs baseline: 1.1311x; 1.1311x over previous
//
#include <hip/hip_runtime.h>
#include <hip/hip_bf16.h>
#include <stdint.h>

// Problem dims (fixed by setup_inputs)
#define B_N 4096
#define S_N 8192
#define KX  256
#define KY  128
// Tiling: 128x128 (batch x sample) tile per block, K fused (256 x + 128 y), BK=32
#define BM 128
#define BN 128

typedef __bf16 bf16x8 __attribute__((ext_vector_type(8)));
typedef float  f32x4  __attribute__((ext_vector_type(4)));

// ---- workspace byte offsets ----
#define OFF_XH   ((size_t)0)            // 4096*256*2 = 2 MB
#define OFF_XL   ((size_t)2097152)
#define OFF_YH   ((size_t)4194304)      // 4096*128*2 = 1 MB
#define OFF_YL   ((size_t)5242880)
#define OFF_SXH  ((size_t)6291456)      // 8192*256*2 = 4 MB
#define OFF_SXL  ((size_t)10485760)
#define OFF_SYH  ((size_t)14680064)     // 8192*128*2 = 2 MB
#define OFF_SYL  ((size_t)16777216)
#define OFF_NX   ((size_t)18874368)     // 4096 f32
#define OFF_NY   (OFF_NX + 16384)
#define OFF_NSX  (OFF_NY + 16384)       // 8192 f32
#define OFF_NSY  (OFF_NSX + 32768)
#define OFF_PART (OFF_NSY + 32768)      // [3][4096][64] float2 = 6.29 MB
#define OFF_BSUM (OFF_PART + (size_t)3*4096*64*2*4)   // 1024 f32
// total ws use ~25.3 MB

__device__ __forceinline__ void gl2lds16(const void* g, void* l) {
  // async global->LDS, 16B per lane; LDS dest = wave-uniform base + lane*16
  typedef const __attribute__((address_space(1))) unsigned int* gp_t;
  typedef __attribute__((address_space(3))) unsigned int* lp_t;
  __builtin_amdgcn_global_load_lds((gp_t)g, (lp_t)l, 16, 0, 0);
}

__device__ __forceinline__ unsigned short f2bf(float f) {
  unsigned u = __builtin_bit_cast(unsigned, f);
  return (unsigned short)((u + 0x7fffu + ((u >> 16) & 1u)) >> 16);
}
__device__ __forceinline__ float bf2f(unsigned short h) {
  return __builtin_bit_cast(float, (unsigned)h << 16);
}

// ---- fused preprocessing: fp32 -> bf16 hi/lo split + fp32 row norms ----
// grid 6144 blocks x 256 thr; one wave per row, vectorized loads/stores.
__global__ __launch_bounds__(256) void conv_all(const float* __restrict__ x,
                                                const float* __restrict__ y,
                                                const float* __restrict__ xs,
                                                const float* __restrict__ ys,
                                                char* __restrict__ ws) {
  int b    = blockIdx.x;
  int wave = threadIdx.x >> 6;
  int lane = threadIdx.x & 63;
  const float* src; unsigned short* hi; unsigned short* lo; float* nrm;
  int K, row;
  if (b < 1024) {
    src = x;  hi = (unsigned short*)(ws + OFF_XH); lo = (unsigned short*)(ws + OFF_XL);
    nrm = (float*)(ws + OFF_NX); K = 256; row = b * 4 + wave;
  } else if (b < 2048) {
    src = y;  hi = (unsigned short*)(ws + OFF_YH); lo = (unsigned short*)(ws + OFF_YL);
    nrm = (float*)(ws + OFF_NY); K = 128; row = (b - 1024) * 4 + wave;
  } else if (b < 4096) {
    src = xs; hi = (unsigned short*)(ws + OFF_SXH); lo = (unsigned short*)(ws + OFF_SXL);
    nrm = (float*)(ws + OFF_NSX); K = 256; row = (b - 2048) * 4 + wave;
  } else {
    src = ys; hi = (unsigned short*)(ws + OFF_SYH); lo = (unsigned short*)(ws + OFF_SYL);
    nrm = (float*)(ws + OFF_NSY); K = 128; row = (b - 4096) * 4 + wave;
  }
  float acc = 0.f;
  if (K == 256) {
    float4 v = ((const float4*)(src + (size_t)row * 256))[lane];
    float vv[4] = {v.x, v.y, v.z, v.w};
    ushort4 h4, l4;
    unsigned short* hp = (unsigned short*)&h4;
    unsigned short* lp = (unsigned short*)&l4;
    #pragma unroll
    for (int k = 0; k < 4; ++k) {
      unsigned short hb = f2bf(vv[k]);
      hp[k] = hb;
      lp[k] = f2bf(vv[k] - bf2f(hb));
      acc = fmaf(vv[k], vv[k], acc);
    }
    ((ushort4*)(hi + (size_t)row * 256))[lane] = h4;
    ((ushort4*)(lo + (size_t)row * 256))[lane] = l4;
  } else {
    float2 v = ((const float2*)(src + (size_t)row * 128))[lane];
    float vv[2] = {v.x, v.y};
    ushort2 h2, l2;
    unsigned short* hp = (unsigned short*)&h2;
    unsigned short* lp = (unsigned short*)&l2;
    #pragma unroll
    for (int k = 0; k < 2; ++k) {
      unsigned short hb = f2bf(vv[k]);
      hp[k] = hb;
      lp[k] = f2bf(vv[k] - bf2f(hb));
      acc = fmaf(vv[k], vv[k], acc);
    }
    ((ushort2*)(hi + (size_t)row * 128))[lane] = h2;
    ((ushort2*)(lo + (size_t)row * 128))[lane] = l2;
  }
  #pragma unroll
  for (int o = 32; o > 0; o >>= 1) acc += __shfl_down(acc, o);
  if (lane == 0) nrm[row] = acc;
}

// ---- main: fused dual-GEMM (x:K=256, y:K=128) + lse epilogue ----
// grid (32, 64); block 256 = 4 waves in 2x2; wave (wm,wn) owns rows wm*64+.., cols wn*64+..
// LDS per K-chunk buffer: Ah 8K | Al 8K | Bh 8K | Bl 8K = 32 KB, double buffered = 64 KB.
// Chunk layout: 128 rows x 64 B; 16B granule g stored at slot g ^ ((r>>1)&3).
__global__ __launch_bounds__(256, 2) void mie_main(const char* __restrict__ ws,
                                                   float* __restrict__ part) {
  __shared__ __align__(16) char smem[65536];

  const int tid  = threadIdx.x;
  const int lane = tid & 63;
  const int wave = tid >> 6;
  const int c    = lane & 15;
  const int q    = lane >> 4;
  const int wm   = wave >> 1;
  const int wn   = wave & 1;
  const int bm0  = blockIdx.x * BM;
  const int sn0  = blockIdx.y * BN;

  const char* xh  = ws + OFF_XH;
  const char* xl  = ws + OFF_XL;
  const char* yh  = ws + OFF_YH;
  const char* yl  = ws + OFF_YL;
  const char* sxh = ws + OFF_SXH;
  const char* sxl = ws + OFF_SXL;
  const char* syh = ws + OFF_SYH;
  const char* syl = ws + OFF_SYL;
  const float* nx  = (const float*)(ws + OFF_NX);
  const float* ny  = (const float*)(ws + OFF_NY);
  const float* nsx = (const float*)(ws + OFF_NSX);
  const float* nsy = (const float*)(ws + OFF_NSY);

  // stage one 32-KB chunk (Ah/Al/Bh/Bl, 8 KB each) into buffer `buf`
  auto stage = [&](int kc, int buf) {
    const char *ah, *al, *bh, *bl; int rb, k0b;
    if (kc < 8) { ah = xh; al = xl; bh = sxh; bl = sxl; rb = 512; k0b = kc * 64; }
    else        { ah = yh; al = yl; bh = syh; bl = syl; rb = 256; k0b = (kc - 8) * 64; }
    char* base = smem + buf * 32768;
    #pragma unroll
    for (int half = 0; half < 2; ++half) {
      int l  = half * 256 + wave * 64 + lane;      // linear 16B slot 0..511
      int r  = l >> 2;
      int sl = l & 3;
      int g  = sl ^ ((r >> 1) & 3);
      size_t kofs = (size_t)k0b + (size_t)g * 16;
      size_t goA  = (size_t)(bm0 + r) * rb + kofs;
      size_t goB  = (size_t)(sn0 + r) * rb + kofs;
      char* dst = base + half * 4096 + wave * 1024;   // wave-uniform
      gl2lds16(ah + goA, dst);
      gl2lds16(al + goA, dst + 8192);
      gl2lds16(bh + goB, dst + 16384);
      gl2lds16(bl + goB, dst + 24576);
    }
  };

  // fragment LDS offsets (row stride 64 B, swizzled slot)
  const int slot = (q ^ ((c >> 1) & 3)) * 16;
  int aoff[4], boff[4];
  #pragma unroll
  for (int i = 0; i < 4; ++i) aoff[i] = (wm * 64 + i * 16 + c) * 64 + slot;
  #pragma unroll
  for (int j = 0; j < 4; ++j) boff[j] = (wn * 64 + j * 16 + c) * 64 + slot;

  f32x4 accx[4][4], accy[4][4];
  #pragma unroll
  for (int i = 0; i < 4; ++i)
    #pragma unroll
    for (int j = 0; j < 4; ++j) {
      accx[i][j] = (f32x4){0.f,0.f,0.f,0.f};
      accy[i][j] = (f32x4){0.f,0.f,0.f,0.f};
    }

  stage(0, 0);
  __syncthreads();

  for (int kc = 0; kc < 12; ++kc) {
    if (kc < 11) stage(kc + 1, (kc + 1) & 1);
    const char* base = smem + (kc & 1) * 32768;
    bf16x8 Ah[4], Al[4], Bh[4], Bl[4];
    #pragma unroll
    for (int i = 0; i < 4; ++i) {
      Ah[i] = *(const bf16x8*)(base + aoff[i]);
      Al[i] = *(const bf16x8*)(base + 8192 + aoff[i]);
    }
    #pragma unroll
    for (int j = 0; j < 4; ++j) {
      Bh[j] = *(const bf16x8*)(base + 16384 + boff[j]);
      Bl[j] = *(const bf16x8*)(base + 24576 + boff[j]);
    }
    if (kc < 8) {
      #pragma unroll
      for (int i = 0; i < 4; ++i)
        #pragma unroll
        for (int j = 0; j < 4; ++j) {
          accx[i][j] = __builtin_amdgcn_mfma_f32_16x16x32_bf16(Ah[i], Bh[j], accx[i][j], 0, 0, 0);
          accx[i][j] = __builtin_amdgcn_mfma_f32_16x16x32_bf16(Ah[i], Bl[j], accx[i][j], 0, 0, 0);
          accx[i][j] = __builtin_amdgcn_mfma_f32_16x16x32_bf16(Al[i], Bh[j], accx[i][j], 0, 0, 0);
        }
    } else {
      #pragma unroll
      for (int i = 0; i < 4; ++i)
        #pragma unroll
        for (int j = 0; j < 4; ++j) {
          accy[i][j] = __builtin_amdgcn_mfma_f32_16x16x32_bf16(Ah[i], Bh[j], accy[i][j], 0, 0, 0);
          accy[i][j] = __builtin_amdgcn_mfma_f32_16x16x32_bf16(Ah[i], Bl[j], accy[i][j], 0, 0, 0);
          accy[i][j] = __builtin_amdgcn_mfma_f32_16x16x32_bf16(Al[i], Bh[j], accy[i][j], 0, 0, 0);
        }
    }
    __syncthreads();
  }

  // ---- epilogue: sd -> 3-stream lse over this block's 128 cols ----
  float nxv[4][4], nyv[4][4];
  #pragma unroll
  for (int i = 0; i < 4; ++i)
    #pragma unroll
    for (int r = 0; r < 4; ++r) {
      int rr = bm0 + wm * 64 + i * 16 + q * 4 + r;
      nxv[i][r] = nx[rr];
      nyv[i][r] = ny[rr];
    }
  float nsxv[4], nsyv[4];
  #pragma unroll
  for (int j = 0; j < 4; ++j) {
    int cc = sn0 + wn * 64 + j * 16 + c;
    nsxv[j] = nsx[cc];
    nsyv[j] = nsy[cc];
  }

  // per-(stream,row_local,wn) partials in LDS: float2 arr[3][128][2]
  float2* xch = (float2*)smem;
  #pragma unroll
  for (int i = 0; i < 4; ++i) {
    #pragma unroll
    for (int r = 0; r < 4; ++r) {
      float vx[4], vy[4];
      #pragma unroll
      for (int j = 0; j < 4; ++j) {
        vx[j] = -0.5f * (nxv[i][r] + nsxv[j] - 2.0f * accx[i][j][r]);
        vy[j] = -0.5f * (nyv[i][r] + nsyv[j] - 2.0f * accy[i][j][r]);
      }
      int rl = wm * 64 + i * 16 + q * 4 + r;
      #pragma unroll
      for (int st = 0; st < 3; ++st) {
        float v0 = (st == 0) ? vx[0] + vy[0] : (st == 1 ? vx[0] : vy[0]);
        float v1 = (st == 0) ? vx[1] + vy[1] : (st == 1 ? vx[1] : vy[1]);
        float v2 = (st == 0) ? vx[2] + vy[2] : (st == 1 ? vx[2] : vy[2]);
        float v3 = (st == 0) ? vx[3] + vy[3] : (st == 1 ? vx[3] : vy[3]);
        float m = fmaxf(fmaxf(v0, v1), fmaxf(v2, v3));
        float s = __expf(v0 - m) + __expf(v1 - m) + __expf(v2 - m) + __expf(v3 - m);
        #pragma unroll
        for (int msk = 1; msk < 16; msk <<= 1) {
          float om = __shfl_xor(m, msk);
          float os = __shfl_xor(s, msk);
          float nm = fmaxf(m, om);
          s = s * __expf(m - nm) + os * __expf(om - nm);
          m = nm;
        }
        if (c == 0) xch[(st * 128 + rl) * 2 + wn] = (float2){m, s};
      }
    }
  }
  __syncthreads();

  // merge the two wn halves, write global partials [3][4096][64] float2
  // 384 entries, 256 threads -> loop (BUGFIX r2: `if (t<384)` left st=2 unwritten)
  for (int t = tid; t < 384; t += 256) {
    int st = t >> 7;
    int rl = t & 127;
    float2 a = xch[(st * 128 + rl) * 2 + 0];
    float2 b = xch[(st * 128 + rl) * 2 + 1];
    float m = fmaxf(a.x, b.x);
    float s = a.y * __expf(a.x - m) + b.y * __expf(b.x - m);
    size_t idx = ((size_t)st * B_N + (bm0 + rl)) * 64 + blockIdx.y;
    ((float2*)part)[idx] = (float2){m, s};
  }
}

// ---- finalize stage 1: per-row lse over 64 partials, per-block sum ----
__global__ __launch_bounds__(256) void fin1(const float* __restrict__ part,
                                            float* __restrict__ bsum) {
  __shared__ float red[4];
  int wave = threadIdx.x >> 6;
  int lane = threadIdx.x & 63;
  int row  = blockIdx.x * 4 + wave;
  float v[3];
  #pragma unroll
  for (int j = 0; j < 3; ++j) {
    const float2* pp = (const float2*)part + ((size_t)j * B_N + row) * 64;
    float2 a = pp[lane];
    float m = a.x, s = a.y;
    #pragma unroll
    for (int msk = 1; msk < 64; msk <<= 1) {
      float om = __shfl_xor(m, msk);
      float os = __shfl_xor(s, msk);
      float nm = fmaxf(m, om);
      s = s * __expf(m - nm) + os * __expf(om - nm);
      m = nm;
    }
    v[j] = m + __logf(s);
  }
  if (lane == 0) red[wave] = v[0] - v[1] - v[2];
  __syncthreads();
  if (threadIdx.x == 0) bsum[blockIdx.x] = red[0] + red[1] + red[2] + red[3];
}

// ---- finalize stage 2: mean over 4096 rows ----
__global__ __launch_bounds__(256) void fin2(const float* __restrict__ bsum,
                                            float* __restrict__ out) {
  __shared__ float red[4];
  int t = threadIdx.x;
  float a = bsum[t] + bsum[t + 256] + bsum[t + 512] + bsum[t + 768];
  #pragma unroll
  for (int o = 32; o > 0; o >>= 1) a += __shfl_down(a, o);
  int wave = t >> 6, lane = t & 63;
  if (lane == 0) red[wave] = a;
  __syncthreads();
  if (t == 0) out[0] = (red[0] + red[1] + red[2] + red[3]) * (1.0f / (float)B_N);
}

extern "C" void kernel_launch(void* const* d_in, const int* in_sizes, int n_in,
                              void* d_out, int out_size, void* d_ws, size_t ws_size,
                              hipStream_t stream) {
  (void)in_sizes; (void)n_in; (void)out_size; (void)ws_size;
  const float* x  = (const float*)d_in[0];
  const float* y  = (const float*)d_in[1];
  const float* xs = (const float*)d_in[2];
  const float* ys = (const float*)d_in[3];
  char* ws = (char*)d_ws;

  conv_all<<<6144, 256, 0, stream>>>(x, y, xs, ys, ws);
  mie_main<<<dim3(B_N / BM, S_N / BN), 256, 0, stream>>>(ws, (float*)(ws + OFF_PART));
  fin1<<<B_N / 4, 256, 0, stream>>>((const float*)(ws + OFF_PART), (float*)(ws + OFF_BSUM));
  fin2<<<1, 256, 0, stream>>>((const float*)(ws + OFF_BSUM), (float*)d_out);
}

// Round 4
// 173.680 us; speedup vs baseline: 1.6430x; 1.4526x over previous
//
#include <hip/hip_runtime.h>
#include <hip/hip_bf16.h>
#include <stdint.h>

// Problem dims (fixed by setup_inputs)
#define B_N 4096
#define S_N 8192
#define KX  256
#define KY  128
// Tiling: 128x128 (batch x sample) tile per block, K fused (256 x + 128 y), BK=32
#define BM 128
#define BN 128

typedef __bf16 bf16x8 __attribute__((ext_vector_type(8)));
typedef float  f32x4  __attribute__((ext_vector_type(4)));

// ---- workspace byte offsets (single-precision-pass bf16: hi only) ----
#define OFF_XH   ((size_t)0)            // 4096*256*2 = 2 MB
#define OFF_YH   ((size_t)2097152)      // 4096*128*2 = 1 MB
#define OFF_SXH  ((size_t)3145728)      // 8192*256*2 = 4 MB
#define OFF_SYH  ((size_t)7340032)      // 8192*128*2 = 2 MB
#define OFF_NX   ((size_t)9437184)      // 4096 f32
#define OFF_NY   (OFF_NX + 16384)
#define OFF_NSX  (OFF_NY + 16384)       // 8192 f32
#define OFF_NSY  (OFF_NSX + 32768)
#define OFF_PART (OFF_NSY + 32768)      // [3][64][4096] float2 = 6.29 MB
#define OFF_BSUM (OFF_PART + (size_t)3*64*4096*2*4)   // 16 f32
// total ws use ~15.8 MB

__device__ __forceinline__ void gl2lds16(const void* g, void* l) {
  // async global->LDS, 16B per lane; LDS dest = wave-uniform base + lane*16
  typedef const __attribute__((address_space(1))) unsigned int* gp_t;
  typedef __attribute__((address_space(3))) unsigned int* lp_t;
  __builtin_amdgcn_global_load_lds((gp_t)g, (lp_t)l, 16, 0, 0);
}

__device__ __forceinline__ unsigned short f2bf(float f) {
  unsigned u = __builtin_bit_cast(unsigned, f);
  return (unsigned short)((u + 0x7fffu + ((u >> 16) & 1u)) >> 16);
}

// ---- preprocessing: fp32 -> bf16 (round-nearest) + fp32 row norms ----
__global__ __launch_bounds__(256) void conv_all(const float* __restrict__ x,
                                                const float* __restrict__ y,
                                                const float* __restrict__ xs,
                                                const float* __restrict__ ys,
                                                char* __restrict__ ws) {
  int b    = blockIdx.x;
  int wave = threadIdx.x >> 6;
  int lane = threadIdx.x & 63;
  const float* src; unsigned short* hi; float* nrm;
  int K, row;
  if (b < 1024) {
    src = x;  hi = (unsigned short*)(ws + OFF_XH);
    nrm = (float*)(ws + OFF_NX); K = 256; row = b * 4 + wave;
  } else if (b < 2048) {
    src = y;  hi = (unsigned short*)(ws + OFF_YH);
    nrm = (float*)(ws + OFF_NY); K = 128; row = (b - 1024) * 4 + wave;
  } else if (b < 4096) {
    src = xs; hi = (unsigned short*)(ws + OFF_SXH);
    nrm = (float*)(ws + OFF_NSX); K = 256; row = (b - 2048) * 4 + wave;
  } else {
    src = ys; hi = (unsigned short*)(ws + OFF_SYH);
    nrm = (float*)(ws + OFF_NSY); K = 128; row = (b - 4096) * 4 + wave;
  }
  float acc = 0.f;
  if (K == 256) {
    float4 v = ((const float4*)(src + (size_t)row * 256))[lane];
    float vv[4] = {v.x, v.y, v.z, v.w};
    ushort4 h4;
    unsigned short* hp = (unsigned short*)&h4;
    #pragma unroll
    for (int k = 0; k < 4; ++k) {
      hp[k] = f2bf(vv[k]);
      acc = fmaf(vv[k], vv[k], acc);
    }
    ((ushort4*)(hi + (size_t)row * 256))[lane] = h4;
  } else {
    float2 v = ((const float2*)(src + (size_t)row * 128))[lane];
    float vv[2] = {v.x, v.y};
    ushort2 h2;
    unsigned short* hp = (unsigned short*)&h2;
    #pragma unroll
    for (int k = 0; k < 2; ++k) {
      hp[k] = f2bf(vv[k]);
      acc = fmaf(vv[k], vv[k], acc);
    }
    ((ushort2*)(hi + (size_t)row * 128))[lane] = h2;
  }
  #pragma unroll
  for (int o = 32; o > 0; o >>= 1) acc += __shfl_down(acc, o);
  if (lane == 0) nrm[row] = acc;
}

// ---- main: fused dual-GEMM (x:K=256, y:K=128) + lse epilogue, single-pass bf16 ----
// grid 2048 linear, XCD-swizzled: xcd=b&7 owns sn-tiles [xcd*8, xcd*8+8) (B-group
// 768 KB resident in its L2); bm streams with 8x consecutive reuse.
// LDS per buffer: A 8K | B 8K = 16 KB, double buffered = 32 KB.
// Chunk layout: 128 rows x 64 B; 16B granule g stored at slot g ^ ((r>>1)&3).
__global__ __launch_bounds__(256, 2) void mie_main(const char* __restrict__ ws,
                                                   float* __restrict__ part) {
  __shared__ __align__(16) char smem[32768];

  const int tid  = threadIdx.x;
  const int lane = tid & 63;
  const int wave = tid >> 6;
  const int c    = lane & 15;
  const int q    = lane >> 4;
  const int wm   = wave >> 1;
  const int wn   = wave & 1;

  const int b     = blockIdx.x;
  const int xcd   = b & 7;
  const int w     = b >> 3;
  const int sn_t  = xcd * 8 + (w & 7);   // 0..63
  const int bm_t  = w >> 3;              // 0..31
  const int bm0   = bm_t * BM;
  const int sn0   = sn_t * BN;

  const char* xh  = ws + OFF_XH;
  const char* yh  = ws + OFF_YH;
  const char* sxh = ws + OFF_SXH;
  const char* syh = ws + OFF_SYH;
  const float* nx  = (const float*)(ws + OFF_NX);
  const float* ny  = (const float*)(ws + OFF_NY);
  const float* nsx = (const float*)(ws + OFF_NSX);
  const float* nsy = (const float*)(ws + OFF_NSY);

  // stage one 16-KB chunk (A 8K, B 8K) into buffer `buf`
  auto stage = [&](int kc, int buf) {
    const char *ah, *bh; int rb, k0b;
    if (kc < 8) { ah = xh; bh = sxh; rb = 512; k0b = kc * 64; }
    else        { ah = yh; bh = syh; rb = 256; k0b = (kc - 8) * 64; }
    char* base = smem + buf * 16384;
    #pragma unroll
    for (int half = 0; half < 2; ++half) {
      int l  = half * 256 + wave * 64 + lane;      // linear 16B slot 0..511
      int r  = l >> 2;
      int sl = l & 3;
      int g  = sl ^ ((r >> 1) & 3);
      size_t kofs = (size_t)k0b + (size_t)g * 16;
      size_t goA  = (size_t)(bm0 + r) * rb + kofs;
      size_t goB  = (size_t)(sn0 + r) * rb + kofs;
      char* dst = base + half * 4096 + wave * 1024;   // wave-uniform
      gl2lds16(ah + goA, dst);
      gl2lds16(bh + goB, dst + 8192);
    }
  };

  // fragment LDS offsets (row stride 64 B, swizzled slot)
  const int slot = (q ^ ((c >> 1) & 3)) * 16;
  int aoff[4], boff[4];
  #pragma unroll
  for (int i = 0; i < 4; ++i) aoff[i] = (wm * 64 + i * 16 + c) * 64 + slot;
  #pragma unroll
  for (int j = 0; j < 4; ++j) boff[j] = (wn * 64 + j * 16 + c) * 64 + slot;

  f32x4 accx[4][4], accy[4][4];
  #pragma unroll
  for (int i = 0; i < 4; ++i)
    #pragma unroll
    for (int j = 0; j < 4; ++j) {
      accx[i][j] = (f32x4){0.f,0.f,0.f,0.f};
      accy[i][j] = (f32x4){0.f,0.f,0.f,0.f};
    }

  stage(0, 0);
  __syncthreads();

  for (int kc = 0; kc < 12; ++kc) {
    if (kc < 11) stage(kc + 1, (kc + 1) & 1);
    const char* base = smem + (kc & 1) * 16384;
    bf16x8 Ah[4], Bh[4];
    #pragma unroll
    for (int i = 0; i < 4; ++i) Ah[i] = *(const bf16x8*)(base + aoff[i]);
    #pragma unroll
    for (int j = 0; j < 4; ++j) Bh[j] = *(const bf16x8*)(base + 8192 + boff[j]);
    if (kc < 8) {
      #pragma unroll
      for (int i = 0; i < 4; ++i)
        #pragma unroll
        for (int j = 0; j < 4; ++j)
          accx[i][j] = __builtin_amdgcn_mfma_f32_16x16x32_bf16(Ah[i], Bh[j], accx[i][j], 0, 0, 0);
    } else {
      #pragma unroll
      for (int i = 0; i < 4; ++i)
        #pragma unroll
        for (int j = 0; j < 4; ++j)
          accy[i][j] = __builtin_amdgcn_mfma_f32_16x16x32_bf16(Ah[i], Bh[j], accy[i][j], 0, 0, 0);
    }
    __syncthreads();
  }

  // ---- epilogue: sd -> 3-stream lse over this block's 128 cols ----
  float nxv[4][4], nyv[4][4];
  #pragma unroll
  for (int i = 0; i < 4; ++i)
    #pragma unroll
    for (int r = 0; r < 4; ++r) {
      int rr = bm0 + wm * 64 + i * 16 + q * 4 + r;
      nxv[i][r] = nx[rr];
      nyv[i][r] = ny[rr];
    }
  float nsxv[4], nsyv[4];
  #pragma unroll
  for (int j = 0; j < 4; ++j) {
    int cc = sn0 + wn * 64 + j * 16 + c;
    nsxv[j] = nsx[cc];
    nsyv[j] = nsy[cc];
  }

  // per-(stream,row_local,wn) partials in LDS: float2 arr[3][128][2]
  float2* xch = (float2*)smem;
  #pragma unroll
  for (int i = 0; i < 4; ++i) {
    #pragma unroll
    for (int r = 0; r < 4; ++r) {
      float vx[4], vy[4];
      #pragma unroll
      for (int j = 0; j < 4; ++j) {
        vx[j] = -0.5f * (nxv[i][r] + nsxv[j] - 2.0f * accx[i][j][r]);
        vy[j] = -0.5f * (nyv[i][r] + nsyv[j] - 2.0f * accy[i][j][r]);
      }
      int rl = wm * 64 + i * 16 + q * 4 + r;
      #pragma unroll
      for (int st = 0; st < 3; ++st) {
        float v0 = (st == 0) ? vx[0] + vy[0] : (st == 1 ? vx[0] : vy[0]);
        float v1 = (st == 0) ? vx[1] + vy[1] : (st == 1 ? vx[1] : vy[1]);
        float v2 = (st == 0) ? vx[2] + vy[2] : (st == 1 ? vx[2] : vy[2]);
        float v3 = (st == 0) ? vx[3] + vy[3] : (st == 1 ? vx[3] : vy[3]);
        float m = fmaxf(fmaxf(v0, v1), fmaxf(v2, v3));
        float s = __expf(v0 - m) + __expf(v1 - m) + __expf(v2 - m) + __expf(v3 - m);
        #pragma unroll
        for (int msk = 1; msk < 16; msk <<= 1) {
          float om = __shfl_xor(m, msk);
          float os = __shfl_xor(s, msk);
          float nm = fmaxf(m, om);
          s = s * __expf(m - nm) + os * __expf(om - nm);
          m = nm;
        }
        if (c == 0) xch[(st * 128 + rl) * 2 + wn] = (float2){m, s};
      }
    }
  }
  __syncthreads();

  // merge the two wn halves; write coalesced partials: [3][64][4096] float2
  for (int t = tid; t < 384; t += 256) {
    int st = t >> 7;
    int rl = t & 127;
    float2 a = xch[(st * 128 + rl) * 2 + 0];
    float2 bb = xch[(st * 128 + rl) * 2 + 1];
    float m = fmaxf(a.x, bb.x);
    float s = a.y * __expf(a.x - m) + bb.y * __expf(bb.x - m);
    size_t idx = ((size_t)st * 64 + sn_t) * B_N + (bm0 + rl);
    ((float2*)part)[idx] = (float2){m, s};
  }
}

// ---- finalize stage 1: per-row lse over 64 partials (coalesced), block sum ----
__global__ __launch_bounds__(256) void fin1(const float* __restrict__ part,
                                            float* __restrict__ bsum) {
  __shared__ float red[4];
  int tid = threadIdx.x;
  int row = blockIdx.x * 256 + tid;
  float v[3];
  #pragma unroll
  for (int j = 0; j < 3; ++j) {
    float m = -__builtin_inff(), s = 0.f;
    for (int p = 0; p < 64; ++p) {
      float2 a = ((const float2*)part)[((size_t)j * 64 + p) * B_N + row];
      float nm = fmaxf(m, a.x);
      s = s * __expf(m - nm) + a.y * __expf(a.x - nm);
      m = nm;
    }
    v[j] = m + __logf(s);
  }
  float local = v[0] - v[1] - v[2];
  #pragma unroll
  for (int o = 32; o > 0; o >>= 1) local += __shfl_down(local, o);
  int wave = tid >> 6, lane = tid & 63;
  if (lane == 0) red[wave] = local;
  __syncthreads();
  if (tid == 0) bsum[blockIdx.x] = red[0] + red[1] + red[2] + red[3];
}

// ---- finalize stage 2: mean over 4096 rows ----
__global__ void fin2(const float* __restrict__ bsum, float* __restrict__ out) {
  int t = threadIdx.x;
  float a = (t < 16) ? bsum[t] : 0.f;
  #pragma unroll
  for (int o = 8; o > 0; o >>= 1) a += __shfl_down(a, o);
  if (t == 0) out[0] = a * (1.0f / (float)B_N);
}

extern "C" void kernel_launch(void* const* d_in, const int* in_sizes, int n_in,
                              void* d_out, int out_size, void* d_ws, size_t ws_size,
                              hipStream_t stream) {
  (void)in_sizes; (void)n_in; (void)out_size; (void)ws_size;
  const float* x  = (const float*)d_in[0];
  const float* y  = (const float*)d_in[1];
  const float* xs = (const float*)d_in[2];
  const float* ys = (const float*)d_in[3];
  char* ws = (char*)d_ws;

  conv_all<<<6144, 256, 0, stream>>>(x, y, xs, ys, ws);
  mie_main<<<2048, 256, 0, stream>>>(ws, (float*)(ws + OFF_PART));
  fin1<<<B_N / 256, 256, 0, stream>>>((const float*)(ws + OFF_PART), (float*)(ws + OFF_BSUM));
  fin2<<<1, 64, 0, stream>>>((const float*)(ws + OFF_BSUM), (float*)d_out);
}

// Round 5
// 143.947 us; speedup vs baseline: 1.9823x; 1.2066x over previous
//
#include <hip/hip_runtime.h>
#include <hip/hip_bf16.h>
#include <stdint.h>

// Problem dims (fixed by setup_inputs)
#define B_N 4096
#define S_N 8192
#define KX  256
#define KY  128
// Tiling: 128x128 (batch x sample) tile per block, K fused (256 x + 128 y), BK=32
#define BM 128
#define BN 128

typedef __bf16 bf16x8 __attribute__((ext_vector_type(8)));
typedef float  f32x4  __attribute__((ext_vector_type(4)));

// ---- workspace byte offsets ----
#define OFF_XH   ((size_t)0)            // 4096*256*2 = 2 MB
#define OFF_YH   ((size_t)2097152)      // 4096*128*2 = 1 MB
#define OFF_SXH  ((size_t)3145728)      // 8192*256*2 = 4 MB
#define OFF_SYH  ((size_t)7340032)      // 8192*128*2 = 2 MB
#define OFF_NX   ((size_t)9437184)      // 4096 f32
#define OFF_NY   (OFF_NX + 16384)
#define OFF_NSX  (OFF_NY + 16384)       // 8192 f32
#define OFF_NSY  (OFF_NSX + 32768)
#define OFF_PART (OFF_NSY + 32768)      // [3][64][4096] float2 = 6.29 MB
#define OFF_BSUM (OFF_PART + (size_t)3*64*4096*2*4)   // 64 f32

__device__ __forceinline__ void gl2lds16(const void* g, void* l) {
  // async global->LDS, 16B per lane; LDS dest = wave-uniform base + lane*16
  typedef const __attribute__((address_space(1))) unsigned int* gp_t;
  typedef __attribute__((address_space(3))) unsigned int* lp_t;
  __builtin_amdgcn_global_load_lds((gp_t)g, (lp_t)l, 16, 0, 0);
}

__device__ __forceinline__ unsigned short f2bf(float f) {
  unsigned u = __builtin_bit_cast(unsigned, f);
  return (unsigned short)((u + 0x7fffu + ((u >> 16) & 1u)) >> 16);
}

// ---- preprocessing: fp32 -> bf16 (round-nearest) + fp32 row norms ----
__global__ __launch_bounds__(256) void conv_all(const float* __restrict__ x,
                                                const float* __restrict__ y,
                                                const float* __restrict__ xs,
                                                const float* __restrict__ ys,
                                                char* __restrict__ ws) {
  int b    = blockIdx.x;
  int wave = threadIdx.x >> 6;
  int lane = threadIdx.x & 63;
  const float* src; unsigned short* hi; float* nrm;
  int K, row;
  if (b < 1024) {
    src = x;  hi = (unsigned short*)(ws + OFF_XH);
    nrm = (float*)(ws + OFF_NX); K = 256; row = b * 4 + wave;
  } else if (b < 2048) {
    src = y;  hi = (unsigned short*)(ws + OFF_YH);
    nrm = (float*)(ws + OFF_NY); K = 128; row = (b - 1024) * 4 + wave;
  } else if (b < 4096) {
    src = xs; hi = (unsigned short*)(ws + OFF_SXH);
    nrm = (float*)(ws + OFF_NSX); K = 256; row = (b - 2048) * 4 + wave;
  } else {
    src = ys; hi = (unsigned short*)(ws + OFF_SYH);
    nrm = (float*)(ws + OFF_NSY); K = 128; row = (b - 4096) * 4 + wave;
  }
  float acc = 0.f;
  if (K == 256) {
    float4 v = ((const float4*)(src + (size_t)row * 256))[lane];
    float vv[4] = {v.x, v.y, v.z, v.w};
    ushort4 h4;
    unsigned short* hp = (unsigned short*)&h4;
    #pragma unroll
    for (int k = 0; k < 4; ++k) {
      hp[k] = f2bf(vv[k]);
      acc = fmaf(vv[k], vv[k], acc);
    }
    ((ushort4*)(hi + (size_t)row * 256))[lane] = h4;
  } else {
    float2 v = ((const float2*)(src + (size_t)row * 128))[lane];
    float vv[2] = {v.x, v.y};
    ushort2 h2;
    unsigned short* hp = (unsigned short*)&h2;
    #pragma unroll
    for (int k = 0; k < 2; ++k) {
      hp[k] = f2bf(vv[k]);
      acc = fmaf(vv[k], vv[k], acc);
    }
    ((ushort2*)(hi + (size_t)row * 128))[lane] = h2;
  }
  #pragma unroll
  for (int o = 32; o > 0; o >>= 1) acc += __shfl_down(acc, o);
  if (lane == 0) nrm[row] = acc;
}

// ---- main: fused dual-GEMM (x:K=256, y:K=128) + max-first lse epilogue ----
// 512 threads = 8 waves in 4x2: wave (wm,wn) owns rows wm*32+[0,32), cols wn*64+[0,64).
// acc = 64 VGPR/lane -> __launch_bounds__(512,4): 4 waves/SIMD, 2 blocks/CU.
// LDS per buffer: A 8K | B 8K = 16 KB, double buffered = 32 KB.
// Chunk layout: 128 rows x 64 B; 16B granule g stored at slot g ^ ((r>>1)&3).
// XCD swizzle: xcd=b&7; bm fast-varying so each XCD's A set (3 MB) + B stay L2-hot.
__global__ __launch_bounds__(512, 4) void mie_main(const char* __restrict__ ws,
                                                   float* __restrict__ part) {
  __shared__ __align__(16) char smem[32768];

  const int tid  = threadIdx.x;
  const int lane = tid & 63;
  const int wave = tid >> 6;
  const int c    = lane & 15;
  const int q    = lane >> 4;
  const int wm   = wave >> 1;   // 0..3
  const int wn   = wave & 1;    // 0..1

  const int b     = blockIdx.x;
  const int xcd   = b & 7;
  const int w     = b >> 3;              // 0..255
  const int bm_t  = w & 31;              // fast: A streams, stays L2-resident
  const int sn_t  = xcd * 8 + (w >> 5);  // 0..63
  const int bm0   = bm_t * BM;
  const int sn0   = sn_t * BN;

  const char* xh  = ws + OFF_XH;
  const char* yh  = ws + OFF_YH;
  const char* sxh = ws + OFF_SXH;
  const char* syh = ws + OFF_SYH;
  const float* nx  = (const float*)(ws + OFF_NX);
  const float* ny  = (const float*)(ws + OFF_NY);
  const float* nsx = (const float*)(ws + OFF_NSX);
  const float* nsy = (const float*)(ws + OFF_NSY);

  // stage one 16-KB chunk (A 8K, B 8K): 512 lanes x 1 granule each side
  auto stage = [&](int kc, int buf) {
    const char *ah, *bh; int rb, k0b;
    if (kc < 8) { ah = xh; bh = sxh; rb = 512; k0b = kc * 64; }
    else        { ah = yh; bh = syh; rb = 256; k0b = (kc - 8) * 64; }
    char* base = smem + buf * 16384;
    int l  = wave * 64 + lane;           // linear 16B slot 0..511
    int r  = l >> 2;
    int sl = l & 3;
    int g  = sl ^ ((r >> 1) & 3);
    size_t kofs = (size_t)k0b + (size_t)g * 16;
    size_t goA  = (size_t)(bm0 + r) * rb + kofs;
    size_t goB  = (size_t)(sn0 + r) * rb + kofs;
    char* dst = base + wave * 1024;      // wave-uniform + lane*16
    gl2lds16(ah + goA, dst);
    gl2lds16(bh + goB, dst + 8192);
  };

  // fragment LDS offsets (row stride 64 B, swizzled slot)
  const int slot = (q ^ ((c >> 1) & 3)) * 16;
  int aoff[2], boff[4];
  #pragma unroll
  for (int i = 0; i < 2; ++i) aoff[i] = (wm * 32 + i * 16 + c) * 64 + slot;
  #pragma unroll
  for (int j = 0; j < 4; ++j) boff[j] = (wn * 64 + j * 16 + c) * 64 + slot;

  f32x4 accx[2][4], accy[2][4];
  #pragma unroll
  for (int i = 0; i < 2; ++i)
    #pragma unroll
    for (int j = 0; j < 4; ++j) {
      accx[i][j] = (f32x4){0.f,0.f,0.f,0.f};
      accy[i][j] = (f32x4){0.f,0.f,0.f,0.f};
    }

  stage(0, 0);
  __syncthreads();

  for (int kc = 0; kc < 12; ++kc) {
    if (kc < 11) stage(kc + 1, (kc + 1) & 1);
    const char* base = smem + (kc & 1) * 16384;
    bf16x8 Ah[2], Bh[4];
    #pragma unroll
    for (int i = 0; i < 2; ++i) Ah[i] = *(const bf16x8*)(base + aoff[i]);
    #pragma unroll
    for (int j = 0; j < 4; ++j) Bh[j] = *(const bf16x8*)(base + 8192 + boff[j]);
    if (kc < 8) {
      #pragma unroll
      for (int i = 0; i < 2; ++i)
        #pragma unroll
        for (int j = 0; j < 4; ++j)
          accx[i][j] = __builtin_amdgcn_mfma_f32_16x16x32_bf16(Ah[i], Bh[j], accx[i][j], 0, 0, 0);
    } else {
      #pragma unroll
      for (int i = 0; i < 2; ++i)
        #pragma unroll
        for (int j = 0; j < 4; ++j)
          accy[i][j] = __builtin_amdgcn_mfma_f32_16x16x32_bf16(Ah[i], Bh[j], accy[i][j], 0, 0, 0);
    }
    __syncthreads();
  }

  // ---- epilogue: v = acc - 0.5*(||a||^2 + ||b||^2); max-first lse ----
  float hxv[2][4], hyv[2][4];
  #pragma unroll
  for (int i = 0; i < 2; ++i)
    #pragma unroll
    for (int r = 0; r < 4; ++r) {
      int rr = bm0 + wm * 32 + i * 16 + q * 4 + r;
      hxv[i][r] = -0.5f * nx[rr];
      hyv[i][r] = -0.5f * ny[rr];
    }
  float hsxv[4], hsyv[4];
  #pragma unroll
  for (int j = 0; j < 4; ++j) {
    int cc = sn0 + wn * 64 + j * 16 + c;
    hsxv[j] = -0.5f * nsx[cc];
    hsyv[j] = -0.5f * nsy[cc];
  }

  // per-(stream,row_local,wn) partials in LDS: float2 arr[3][128][2]
  float2* xch = (float2*)smem;
  #pragma unroll
  for (int i = 0; i < 2; ++i) {
    #pragma unroll
    for (int r = 0; r < 4; ++r) {
      float vx[4], vy[4];
      #pragma unroll
      for (int j = 0; j < 4; ++j) {
        vx[j] = accx[i][j][r] + hxv[i][r] + hsxv[j];
        vy[j] = accy[i][j][r] + hyv[i][r] + hsyv[j];
      }
      int rl = wm * 32 + i * 16 + q * 4 + r;
      #pragma unroll
      for (int st = 0; st < 3; ++st) {
        float v0 = (st == 0) ? vx[0] + vy[0] : (st == 1 ? vx[0] : vy[0]);
        float v1 = (st == 0) ? vx[1] + vy[1] : (st == 1 ? vx[1] : vy[1]);
        float v2 = (st == 0) ? vx[2] + vy[2] : (st == 1 ? vx[2] : vy[2]);
        float v3 = (st == 0) ? vx[3] + vy[3] : (st == 1 ? vx[3] : vy[3]);
        // 1) uniform max over the 64 cols (cheap fmax shuffles)
        float m = fmaxf(fmaxf(v0, v1), fmaxf(v2, v3));
        #pragma unroll
        for (int msk = 1; msk < 16; msk <<= 1) m = fmaxf(m, __shfl_xor(m, msk));
        // 2) 4 exps with shared max, then sum shuffles
        float s = __expf(v0 - m) + __expf(v1 - m) + __expf(v2 - m) + __expf(v3 - m);
        #pragma unroll
        for (int msk = 1; msk < 16; msk <<= 1) s += __shfl_xor(s, msk);
        if (c == 0) xch[(st * 128 + rl) * 2 + wn] = (float2){m, s};
      }
    }
  }
  __syncthreads();

  // merge the two wn halves; write coalesced partials: [3][64][4096] float2
  if (tid < 384) {
    int st = tid >> 7;
    int rl = tid & 127;
    float2 a = xch[(st * 128 + rl) * 2 + 0];
    float2 bb = xch[(st * 128 + rl) * 2 + 1];
    float m = fmaxf(a.x, bb.x);
    float s = a.y * __expf(a.x - m) + bb.y * __expf(bb.x - m);
    size_t idx = ((size_t)st * 64 + sn_t) * B_N + (bm0 + rl);
    ((float2*)part)[idx] = (float2){m, s};
  }
}

// ---- finalize stage 1: per-row lse over 64 partials, 4 waves split p-range ----
__global__ __launch_bounds__(256) void fin1(const float* __restrict__ part,
                                            float* __restrict__ bsum) {
  __shared__ float2 lds[3][4][64];
  int tid  = threadIdx.x;
  int wave = tid >> 6;
  int lane = tid & 63;
  int row  = blockIdx.x * 64 + lane;
  #pragma unroll
  for (int j = 0; j < 3; ++j) {
    float m = -__builtin_inff(), s = 0.f;
    #pragma unroll
    for (int pp = 0; pp < 16; ++pp) {
      int p = wave * 16 + pp;
      float2 a = ((const float2*)part)[((size_t)j * 64 + p) * B_N + row];
      float nm = fmaxf(m, a.x);
      s = s * __expf(m - nm) + a.y * __expf(a.x - nm);
      m = nm;
    }
    lds[j][wave][lane] = (float2){m, s};
  }
  __syncthreads();
  if (wave == 0) {
    float v[3];
    #pragma unroll
    for (int j = 0; j < 3; ++j) {
      float m = -__builtin_inff(), s = 0.f;
      #pragma unroll
      for (int u = 0; u < 4; ++u) {
        float2 a = lds[j][u][lane];
        float nm = fmaxf(m, a.x);
        s = s * __expf(m - nm) + a.y * __expf(a.x - nm);
        m = nm;
      }
      v[j] = m + __logf(s);
    }
    float local = v[0] - v[1] - v[2];
    #pragma unroll
    for (int o = 32; o > 0; o >>= 1) local += __shfl_down(local, o);
    if (lane == 0) bsum[blockIdx.x] = local;
  }
}

// ---- finalize stage 2: mean over 4096 rows (64 block sums) ----
__global__ void fin2(const float* __restrict__ bsum, float* __restrict__ out) {
  int t = threadIdx.x;
  float a = bsum[t];
  #pragma unroll
  for (int o = 32; o > 0; o >>= 1) a += __shfl_down(a, o);
  if (t == 0) out[0] = a * (1.0f / (float)B_N);
}

extern "C" void kernel_launch(void* const* d_in, const int* in_sizes, int n_in,
                              void* d_out, int out_size, void* d_ws, size_t ws_size,
                              hipStream_t stream) {
  (void)in_sizes; (void)n_in; (void)out_size; (void)ws_size;
  const float* x  = (const float*)d_in[0];
  const float* y  = (const float*)d_in[1];
  const float* xs = (const float*)d_in[2];
  const float* ys = (const float*)d_in[3];
  char* ws = (char*)d_ws;

  conv_all<<<6144, 256, 0, stream>>>(x, y, xs, ys, ws);
  mie_main<<<2048, 512, 0, stream>>>(ws, (float*)(ws + OFF_PART));
  fin1<<<B_N / 64, 256, 0, stream>>>((const float*)(ws + OFF_PART), (float*)(ws + OFF_BSUM));
  fin2<<<1, 64, 0, stream>>>((const float*)(ws + OFF_BSUM), (float*)d_out);
}